// Round 5
// baseline (1738.782 us; speedup 1.0000x reference)
//
#include <hip/hip_runtime.h>

// Problem constants: N=5, B=16, H=W=384, J=17
#define NF 5
#define NB 16
#define NH 384
#define NW 384
#define NJ 17
#define HW (NH * NW)
#define PW (NW + 3)                 // padded cols: x = -1 .. 385
#define PH (NH + 3)                 // padded rows: y = -1 .. 385
#define PHW (PH * PW)               // 149769
#define NITEMS (NF * NB * NH * NW)  // 11,796,480
#define UNSUP_BLOCKS (NITEMS / 256) // 46080
#define PACK_TOTAL (NB * PHW)       // 2,396,304

// ws float layout:
//   [0]=sup_sum, [1]=denom, u32[2]=ticket, [3..15] pad
//   [16 + s*32] for s in 0..63 : spread partial-sum slots (128 B apart)
//   float4 packed[PACK_TOTAL] at (float4*)ws + 516   (8256 bytes header)
#define SLOT(ws, s) ((ws) + 16 + (s) * 32)
#define PACKED_OFF 516

// fast charbonnier: (x^2 + 1e-18)^0.25, raw v_sqrt_f32 (~1 ulp; threshold is 2% rel)
__device__ __forceinline__ float charb(float x) {
    return __builtin_amdgcn_sqrtf(__builtin_amdgcn_sqrtf(fmaf(x, x, 1e-18f)));
}

__global__ __launch_bounds__(256)
void repack_kp_kernel(const float* __restrict__ frm1,
                      const float* __restrict__ kps,
                      const float* __restrict__ pf,
                      float* __restrict__ ws, int do_pack) {
    int g = blockIdx.x * 256 + threadIdx.x;
    if (do_pack && g < PACK_TOTAL) {
        int b = g / PHW;
        int r = g - b * PHW;
        int py = r / PW;
        int px = r - py * PW;
        int x = px - 1, y = py - 1;
        float4 v = make_float4(0.f, 0.f, 0.f, 0.f);
        if (x >= 0 && x < NW && y >= 0 && y < NH) {
            const float* src = frm1 + (size_t)b * 3 * HW + y * NW + x;
            v = make_float4(src[0], src[HW], src[2 * HW], 0.f);
        }
        ((float4*)ws)[PACKED_OFF + g] = v;
    }
    if (blockIdx.x == 0) {
        int t = threadIdx.x;
        if (t < 64) *SLOT(ws, t) = 0.f;          // zero the 64 partial slots
        if (t == 0) ((unsigned int*)ws)[2] = 0u; // zero the ticket
        // ---- keypoint supervised loss (sparse: <= 272 points) ----
        __shared__ int cnt;
        __shared__ int ebase[NB * NJ];
        __shared__ float edx[NB * NJ], edy[NB * NJ];
        if (t == 0) cnt = 0;
        __syncthreads();
        for (int q = t; q < NB * NJ; q += 256) {
            int b = q / NJ, j = q - b * NJ;
            const float* k0 = kps + ((b * 2 + 0) * NJ + j) * 2;
            const float* k1 = kps + ((b * 2 + 1) * NJ + j) * 2;
            float x0 = k0[0], y0 = k0[1], x1 = k1[0], y1 = k1[1];
            bool valid = x0 >= 0.f && y0 >= 0.f && x1 >= 0.f && y1 >= 0.f &&
                         x0 < (float)NW && y0 < (float)NH &&
                         x1 < (float)NW && y1 < (float)NH;
            float dx = x1 - x0, dy = y1 - y0;
            if (valid && (dx != 0.f || dy != 0.f)) {
                int s = atomicAdd(&cnt, 1);
                ebase[s] = (b * 2) * HW + (int)floorf(y0) * NW + (int)floorf(x0);
                edx[s] = dx; edy[s] = dy;
            }
        }
        __syncthreads();
        int n = cnt;
        float local = 0.f;
        for (int q = t; q < n * NF; q += 256) {
            int e = q / NF, i = q - e * NF;
            float wt = (i == 0) ? 0.4096f : (i == 1) ? 0.512f :
                       (i == 2) ? 0.64f  : (i == 3) ? 0.8f   : 1.0f;
            int off = ebase[e] + i * (NB * 2 * HW);
            float ex = pf[off] - edx[e];
            float ey = pf[off + HW] - edy[e];
            local += wt * sqrtf(fmaf(ex, ex, ey * ey));
        }
        for (int o = 32; o > 0; o >>= 1) local += __shfl_down(local, o, 64);
        __shared__ float ssum[4];
        int lane = t & 63, wid = t >> 6;
        if (lane == 0) ssum[wid] = local;
        __syncthreads();
        if (t == 0) {
            ws[0] = ssum[0] + ssum[1] + ssum[2] + ssum[3];
            ws[1] = (float)n;
        }
    }
}

// One thread = one (level, pixel). Item order: w fastest, then level i, then b, h
// -> the 5 levels of the same image row dispatch adjacently (L2 reuse of frm0/taps).
template <bool PACKED>
__global__ __launch_bounds__(256, 8)
void unsup_kernel(const float* __restrict__ pf, const float* __restrict__ frm0,
                  const float* __restrict__ frm1,
                  const float4* __restrict__ packed_all,
                  float* __restrict__ ws, float* __restrict__ out) {
    const int idx = blockIdx.x * 256 + threadIdx.x;
    const int w = idx % NW;
    int q = idx / NW;
    const int i = q % NF;
    q = q / NF;
    const int b = q & (NB - 1);
    const int h = q >> 4;
    const int off = h * NW + w;
    const float SC = (float)(NW - 1) / (float)NW;

    // frm0 pixel (coalesced; read once per (pixel,level) but L2-deduped across i)
    const float* f0b = frm0 + b * 3 * HW + off;
    const float c0 = f0b[0];
    const float c1 = f0b[HW];
    const float c2 = f0b[2 * HW];

    // flow + neighbors (coalesced; zero-pad at edges)
    const float* fb = pf + (size_t)((i * NB + b) * 2) * HW + off;
    const float fx = fb[0];
    const float fy = fb[HW];
    float dnx = 0.f, dny = 0.f, rtx = 0.f, rty = 0.f;
    if (h < NH - 1) { dnx = fb[NW]; dny = fb[NW + HW]; }
    if (w < NW - 1) { rtx = fb[1];  rty = fb[HW + 1];  }

    float smooth = charb(fx - dnx) + charb(fy - dny) +
                   charb(fx - rtx) + charb(fy - rty);

    // bilinear zero-pad sample: clamp coords into the stored-zero border,
    // no masks needed (border taps hold 0 = reference's invalid-tap semantics)
    float xp = (fx + (float)w) * SC;
    float yp = (fy + (float)h) * SC;
    float s0, s1, s2;
    if (PACKED) {
        xp = fminf(fmaxf(xp, -1.0f), 384.0f);
        yp = fminf(fmaxf(yp, -1.0f), 384.0f);
        float x0f = floorf(xp), y0f = floorf(yp);
        float wx1 = xp - x0f, wx0 = 1.f - wx1;
        float wy1 = yp - y0f, wy0 = 1.f - wy1;
        int px0 = (int)x0f + 1;              // padded col in [0, 385]
        int py0 = (int)y0f + 1;              // padded row in [0, 385]
        const float4* pk = packed_all + (size_t)b * PHW + py0 * PW + px0;
        float4 t00 = pk[0];
        float4 t10 = pk[1];
        float4 t01 = pk[PW];
        float4 t11 = pk[PW + 1];
        float w00 = wx0 * wy0, w10 = wx1 * wy0;
        float w01 = wx0 * wy1, w11 = wx1 * wy1;
        s0 = w00 * t00.x + w10 * t10.x + w01 * t01.x + w11 * t11.x;
        s1 = w00 * t00.y + w10 * t10.y + w01 * t01.y + w11 * t11.y;
        s2 = w00 * t00.z + w10 * t10.z + w01 * t01.z + w11 * t11.z;
    } else {
        float x0f = floorf(xp), y0f = floorf(yp);
        float wx1 = xp - x0f, wx0 = 1.f - wx1;
        float wy1 = yp - y0f, wy0 = 1.f - wy1;
        bool vx0 = (x0f >= 0.f) && (x0f <= (float)(NW - 1));
        bool vx1 = (x0f >= -1.f) && (x0f <= (float)(NW - 2));
        bool vy0 = (y0f >= 0.f) && (y0f <= (float)(NH - 1));
        bool vy1 = (y0f >= -1.f) && (y0f <= (float)(NH - 2));
        float m00 = (vx0 && vy0) ? wx0 * wy0 : 0.f;
        float m10 = (vx1 && vy0) ? wx1 * wy0 : 0.f;
        float m01 = (vx0 && vy1) ? wx0 * wy1 : 0.f;
        float m11 = (vx1 && vy1) ? wx1 * wy1 : 0.f;
        int x0i = min(max((int)x0f, 0), NW - 1);
        int y0i = min(max((int)y0f, 0), NH - 1);
        int x1i = min(x0i + 1, NW - 1);
        int y1i = min(y0i + 1, NH - 1);
        const float* img = frm1 + b * 3 * HW;
        int i00 = y0i * NW + x0i, i10 = y0i * NW + x1i;
        int i01 = y1i * NW + x0i, i11 = y1i * NW + x1i;
        s0 = m00 * img[i00] + m10 * img[i10] + m01 * img[i01] + m11 * img[i11];
        s1 = m00 * img[HW + i00] + m10 * img[HW + i10] +
             m01 * img[HW + i01] + m11 * img[HW + i11];
        s2 = m00 * img[2 * HW + i00] + m10 * img[2 * HW + i10] +
             m01 * img[2 * HW + i01] + m11 * img[2 * HW + i11];
    }
    float phot = charb(s0 - c0) + charb(s1 - c1) + charb(s2 - c2);

    float wt = (i == 0) ? 0.4096f : (i == 1) ? 0.512f :
               (i == 2) ? 0.64f  : (i == 3) ? 0.8f   : 1.0f;
    float local = wt * fmaf(phot, (1.f / 3.f), smooth * 0.5f);

    // block reduce (256 threads = 4 waves)
    for (int o = 32; o > 0; o >>= 1) local += __shfl_down(local, o, 64);
    __shared__ float ssum[4];
    __shared__ bool amLast;
    int lane = threadIdx.x & 63, wid = threadIdx.x >> 6;
    if (lane == 0) ssum[wid] = local;
    __syncthreads();
    if (threadIdx.x == 0) {
        float s = ssum[0] + ssum[1] + ssum[2] + ssum[3];
        atomicAdd(SLOT(ws, blockIdx.x & 63), s);   // 64 spread slots: no serialization
        __threadfence();
        unsigned int old = atomicAdd((unsigned int*)ws + 2, 1u);
        amLast = (old == (unsigned int)(gridDim.x - 1));
    }
    __syncthreads();
    if (amLast && threadIdx.x < 64) {
        float v = atomicAdd(SLOT(ws, threadIdx.x), 0.f);  // coherent read of slots
        for (int o = 32; o > 0; o >>= 1) v += __shfl_down(v, o, 64);
        if (threadIdx.x == 0) {
            float denom = fmaxf(ws[1], 1.f);
            out[0] = v * (1.f / (float)NB) + ws[0] / denom;
        }
    }
}

extern "C" void kernel_launch(void* const* d_in, const int* in_sizes, int n_in,
                              void* d_out, int out_size, void* d_ws, size_t ws_size,
                              hipStream_t stream) {
    const float* pf   = (const float*)d_in[0];  // (5,16,2,384,384)
    const float* kps  = (const float*)d_in[1];  // (16,2,17,2)
    const float* frm0 = (const float*)d_in[2];  // (16,3,384,384)
    const float* frm1 = (const float*)d_in[3];  // (16,3,384,384)
    float* out = (float*)d_out;
    float* ws  = (float*)d_ws;
    const float4* packed = (const float4*)ws + PACKED_OFF;

    const size_t need = (size_t)PACKED_OFF * 16 + (size_t)PACK_TOTAL * 16;
    if (ws_size >= need) {
        repack_kp_kernel<<<(PACK_TOTAL + 255) / 256, 256, 0, stream>>>(frm1, kps, pf, ws, 1);
        unsup_kernel<true><<<UNSUP_BLOCKS, 256, 0, stream>>>(pf, frm0, frm1, packed, ws, out);
    } else {
        repack_kp_kernel<<<1, 256, 0, stream>>>(frm1, kps, pf, ws, 0);
        unsup_kernel<false><<<UNSUP_BLOCKS, 256, 0, stream>>>(pf, frm0, frm1, packed, ws, out);
    }
}

// Round 9
// 285.209 us; speedup vs baseline: 6.0965x; 6.0965x over previous
//
#include <hip/hip_runtime.h>

// Problem constants: N=5, B=16, H=W=384, J=17
#define NF 5
#define NB 16
#define NH 384
#define NW 384
#define NJ 17
#define HW (NH * NW)
#define PW (NW + 3)                 // padded cols: x = -1 .. 385
#define PH (NH + 3)                 // padded rows: y = -1 .. 385
#define PHW (PH * PW)               // 149769
#define NITEMS (NF * NB * NH * NW)  // 11,796,480
#define UNSUP_BLOCKS (NITEMS / 256) // 46080
#define PACK_TOTAL (NB * PHW)       // 2,396,304

// ws layout:
//   float ws[0]=sup_sum, ws[1]=denom, [2..15] pad   (64 B header)
//   float4 packed[PACK_TOTAL] at (float4*)ws + 4
//   float  partials[UNSUP_BLOCKS] after packed region (or at ws+16 if unpacked)

// fast charbonnier: (x^2 + 1e-18)^0.25 via raw v_sqrt_f32 (~1 ulp; threshold 2% rel)
__device__ __forceinline__ float charb(float x) {
    return __builtin_amdgcn_sqrtf(__builtin_amdgcn_sqrtf(fmaf(x, x, 1e-18f)));
}

__global__ __launch_bounds__(256)
void repack_kp_kernel(const float* __restrict__ frm1,
                      const float* __restrict__ kps,
                      const float* __restrict__ pf,
                      float* __restrict__ ws, int do_pack) {
    int g = blockIdx.x * 256 + threadIdx.x;
    if (do_pack && g < PACK_TOTAL) {
        int b = g / PHW;
        int r = g - b * PHW;
        int py = r / PW;
        int px = r - py * PW;
        int x = px - 1, y = py - 1;
        float4 v = make_float4(0.f, 0.f, 0.f, 0.f);
        if (x >= 0 && x < NW && y >= 0 && y < NH) {
            const float* src = frm1 + (size_t)b * 3 * HW + y * NW + x;
            v = make_float4(src[0], src[HW], src[2 * HW], 0.f);
        }
        ((float4*)ws)[4 + g] = v;
    }
    if (blockIdx.x == 0) {
        int t = threadIdx.x;
        // ---- keypoint supervised loss (sparse: <= 272 points) ----
        __shared__ int cnt;
        __shared__ int ebase[NB * NJ];
        __shared__ float edx[NB * NJ], edy[NB * NJ];
        if (t == 0) cnt = 0;
        __syncthreads();
        for (int q = t; q < NB * NJ; q += 256) {
            int b = q / NJ, j = q - b * NJ;
            const float* k0 = kps + ((b * 2 + 0) * NJ + j) * 2;
            const float* k1 = kps + ((b * 2 + 1) * NJ + j) * 2;
            float x0 = k0[0], y0 = k0[1], x1 = k1[0], y1 = k1[1];
            bool valid = x0 >= 0.f && y0 >= 0.f && x1 >= 0.f && y1 >= 0.f &&
                         x0 < (float)NW && y0 < (float)NH &&
                         x1 < (float)NW && y1 < (float)NH;
            float dx = x1 - x0, dy = y1 - y0;
            if (valid && (dx != 0.f || dy != 0.f)) {
                int s = atomicAdd(&cnt, 1);
                ebase[s] = (b * 2) * HW + (int)floorf(y0) * NW + (int)floorf(x0);
                edx[s] = dx; edy[s] = dy;
            }
        }
        __syncthreads();
        int n = cnt;
        float local = 0.f;
        for (int q = t; q < n * NF; q += 256) {
            int e = q / NF, i = q - e * NF;
            float wt = (i == 0) ? 0.4096f : (i == 1) ? 0.512f :
                       (i == 2) ? 0.64f  : (i == 3) ? 0.8f   : 1.0f;
            int off = ebase[e] + i * (NB * 2 * HW);
            float ex = pf[off] - edx[e];
            float ey = pf[off + HW] - edy[e];
            local += wt * sqrtf(fmaf(ex, ex, ey * ey));
        }
        for (int o = 32; o > 0; o >>= 1) local += __shfl_down(local, o, 64);
        __shared__ float ssum[4];
        int lane = t & 63, wid = t >> 6;
        if (lane == 0) ssum[wid] = local;
        __syncthreads();
        if (t == 0) {
            ws[0] = ssum[0] + ssum[1] + ssum[2] + ssum[3];
            ws[1] = (float)n;
        }
    }
}

// One thread = one (level, pixel). Item order: w fastest, then level i, then b, h
// -> the 5 levels of the same image row dispatch adjacently (L2 reuse of frm0/taps).
// NO atomics / fences: per-block partial store only (round-5 lesson: a fence +
// single-address ticket across 46k blocks serializes ~30 ns each = +1.4 ms).
template <bool PACKED>
__global__ __launch_bounds__(256, 8)
void unsup_kernel(const float* __restrict__ pf, const float* __restrict__ frm0,
                  const float* __restrict__ frm1,
                  const float4* __restrict__ packed_all,
                  float* __restrict__ partials) {
    const int idx = blockIdx.x * 256 + threadIdx.x;
    const int w = idx % NW;
    int q = idx / NW;
    const int i = q % NF;
    q = q / NF;
    const int b = q & (NB - 1);
    const int h = q >> 4;
    const int off = h * NW + w;
    const float SC = (float)(NW - 1) / (float)NW;

    // frm0 pixel (coalesced; L2-deduped across the 5 adjacent-i blocks)
    const float* f0b = frm0 + b * 3 * HW + off;
    const float c0 = f0b[0];
    const float c1 = f0b[HW];
    const float c2 = f0b[2 * HW];

    // flow + neighbors (coalesced; zero-pad at edges)
    const float* fb = pf + (size_t)((i * NB + b) * 2) * HW + off;
    const float fx = fb[0];
    const float fy = fb[HW];
    float dnx = 0.f, dny = 0.f, rtx = 0.f, rty = 0.f;
    if (h < NH - 1) { dnx = fb[NW]; dny = fb[NW + HW]; }
    if (w < NW - 1) { rtx = fb[1];  rty = fb[HW + 1];  }

    float smooth = charb(fx - dnx) + charb(fy - dny) +
                   charb(fx - rtx) + charb(fy - rty);

    // bilinear zero-pad sample of frm1 at (xp, yp)
    float xp = (fx + (float)w) * SC;
    float yp = (fy + (float)h) * SC;
    float s0, s1, s2;
    if (PACKED) {
        // clamp into stored-zero border: all mask/valid logic vanishes
        xp = fminf(fmaxf(xp, -1.0f), 384.0f);
        yp = fminf(fmaxf(yp, -1.0f), 384.0f);
        float x0f = floorf(xp), y0f = floorf(yp);
        float wx1 = xp - x0f, wx0 = 1.f - wx1;
        float wy1 = yp - y0f, wy0 = 1.f - wy1;
        int px0 = (int)x0f + 1;              // padded col in [0, 385]
        int py0 = (int)y0f + 1;              // padded row in [0, 385]
        const float4* pk = packed_all + (size_t)b * PHW + py0 * PW + px0;
        float4 t00 = pk[0];
        float4 t10 = pk[1];
        float4 t01 = pk[PW];
        float4 t11 = pk[PW + 1];
        float w00 = wx0 * wy0, w10 = wx1 * wy0;
        float w01 = wx0 * wy1, w11 = wx1 * wy1;
        s0 = w00 * t00.x + w10 * t10.x + w01 * t01.x + w11 * t11.x;
        s1 = w00 * t00.y + w10 * t10.y + w01 * t01.y + w11 * t11.y;
        s2 = w00 * t00.z + w10 * t10.z + w01 * t01.z + w11 * t11.z;
    } else {
        float x0f = floorf(xp), y0f = floorf(yp);
        float wx1 = xp - x0f, wx0 = 1.f - wx1;
        float wy1 = yp - y0f, wy0 = 1.f - wy1;
        bool vx0 = (x0f >= 0.f) && (x0f <= (float)(NW - 1));
        bool vx1 = (x0f >= -1.f) && (x0f <= (float)(NW - 2));
        bool vy0 = (y0f >= 0.f) && (y0f <= (float)(NH - 1));
        bool vy1 = (y0f >= -1.f) && (y0f <= (float)(NH - 2));
        float m00 = (vx0 && vy0) ? wx0 * wy0 : 0.f;
        float m10 = (vx1 && vy0) ? wx1 * wy0 : 0.f;
        float m01 = (vx0 && vy1) ? wx0 * wy1 : 0.f;
        float m11 = (vx1 && vy1) ? wx1 * wy1 : 0.f;
        int x0i = min(max((int)x0f, 0), NW - 1);
        int y0i = min(max((int)y0f, 0), NH - 1);
        int x1i = min(x0i + 1, NW - 1);
        int y1i = min(y0i + 1, NH - 1);
        const float* img = frm1 + b * 3 * HW;
        int i00 = y0i * NW + x0i, i10 = y0i * NW + x1i;
        int i01 = y1i * NW + x0i, i11 = y1i * NW + x1i;
        s0 = m00 * img[i00] + m10 * img[i10] + m01 * img[i01] + m11 * img[i11];
        s1 = m00 * img[HW + i00] + m10 * img[HW + i10] +
             m01 * img[HW + i01] + m11 * img[HW + i11];
        s2 = m00 * img[2 * HW + i00] + m10 * img[2 * HW + i10] +
             m01 * img[2 * HW + i01] + m11 * img[2 * HW + i11];
    }
    float phot = charb(s0 - c0) + charb(s1 - c1) + charb(s2 - c2);

    float wt = (i == 0) ? 0.4096f : (i == 1) ? 0.512f :
               (i == 2) ? 0.64f  : (i == 3) ? 0.8f   : 1.0f;
    float local = wt * fmaf(phot, (1.f / 3.f), smooth * 0.5f);

    // block reduce (256 threads = 4 waves) -> per-block partial (no atomics)
    for (int o = 32; o > 0; o >>= 1) local += __shfl_down(local, o, 64);
    __shared__ float ssum[4];
    int lane = threadIdx.x & 63, wid = threadIdx.x >> 6;
    if (lane == 0) ssum[wid] = local;
    __syncthreads();
    if (threadIdx.x == 0) {
        partials[blockIdx.x] = ssum[0] + ssum[1] + ssum[2] + ssum[3];
    }
}

__global__ __launch_bounds__(1024)
void final_kernel(const float* __restrict__ ws, const float* __restrict__ partials,
                  float* __restrict__ out) {
    float local = 0.f;
    for (int q = threadIdx.x; q < UNSUP_BLOCKS; q += 1024) local += partials[q];
    for (int o = 32; o > 0; o >>= 1) local += __shfl_down(local, o, 64);
    __shared__ float ssum[16];
    int lane = threadIdx.x & 63, wid = threadIdx.x >> 6;
    if (lane == 0) ssum[wid] = local;
    __syncthreads();
    if (threadIdx.x == 0) {
        float uns = 0.f;
        #pragma unroll
        for (int k = 0; k < 16; ++k) uns += ssum[k];
        float denom = fmaxf(ws[1], 1.f);
        out[0] = uns * (1.f / (float)NB) + ws[0] / denom;
    }
}

extern "C" void kernel_launch(void* const* d_in, const int* in_sizes, int n_in,
                              void* d_out, int out_size, void* d_ws, size_t ws_size,
                              hipStream_t stream) {
    const float* pf   = (const float*)d_in[0];  // (5,16,2,384,384)
    const float* kps  = (const float*)d_in[1];  // (16,2,17,2)
    const float* frm0 = (const float*)d_in[2];  // (16,3,384,384)
    const float* frm1 = (const float*)d_in[3];  // (16,3,384,384)
    float* out = (float*)d_out;
    float* ws  = (float*)d_ws;
    const float4* packed = (const float4*)ws + 4;

    const size_t need = 64 + (size_t)PACK_TOTAL * 16 + (size_t)UNSUP_BLOCKS * 4;
    if (ws_size >= need) {
        float* partials = ws + 16 + (size_t)PACK_TOTAL * 4;
        repack_kp_kernel<<<(PACK_TOTAL + 255) / 256, 256, 0, stream>>>(frm1, kps, pf, ws, 1);
        unsup_kernel<true><<<UNSUP_BLOCKS, 256, 0, stream>>>(pf, frm0, frm1, packed, partials);
        final_kernel<<<1, 1024, 0, stream>>>(ws, partials, out);
    } else {
        float* partials = ws + 16;
        repack_kp_kernel<<<1, 256, 0, stream>>>(frm1, kps, pf, ws, 0);
        unsup_kernel<false><<<UNSUP_BLOCKS, 256, 0, stream>>>(pf, frm0, frm1, packed, partials);
        final_kernel<<<1, 1024, 0, stream>>>(ws, partials, out);
    }
}

// Round 11
// 273.661 us; speedup vs baseline: 6.3538x; 1.0422x over previous
//
#include <hip/hip_runtime.h>

// Problem constants: N=5, B=16, H=W=384, J=17
#define NF 5
#define NB 16
#define NH 384
#define NW 384
#define NJ 17
#define HW (NH * NW)
#define PW (NW + 3)                   // padded cols: x = -1 .. 385
#define PH (NH + 3)
#define PHW (PH * PW)                 // 149769
#define NPIX (NB * HW)                // 2,359,296
#define PACK_TOTAL (NB * PHW)         // 2,396,304
#define NTHREADS2 (NF * NB * NH * (NW / 2))  // 5,898,240
#define UNSUP2_BLOCKS (NTHREADS2 / 256)      // 23040
#define UNSUP1_BLOCKS ((NF * NB * HW) / 256) // 46080 (fallback)

// fast charbonnier: (x^2 + 1e-18)^0.25 via raw v_sqrt_f32 (~1 ulp; threshold 2% rel)
__device__ __forceinline__ float charb(float x) {
    return __builtin_amdgcn_sqrtf(__builtin_amdgcn_sqrtf(fmaf(x, x, 1e-18f)));
}
// f32 -> bf16 (RNE), values are finite [0,1): no NaN handling needed
__device__ __forceinline__ unsigned int f2bf(float f) {
    unsigned int x = __builtin_bit_cast(unsigned int, f);
    x += 0x7FFFu + ((x >> 16) & 1u);
    return x >> 16;
}
__device__ __forceinline__ float bflo(unsigned int u) {  // low 16 bits as bf16
    return __builtin_bit_cast(float, u << 16);
}
__device__ __forceinline__ float bfhi(unsigned int u) {  // high 16 bits as bf16
    return __builtin_bit_cast(float, u & 0xFFFF0000u);
}

// ws layout (bytes):
//   [0..63]   float ws[0]=sup_sum, ws[1]=denom
//   [64 ..)                uint2 packed1[PACK_TOTAL]  (frm1, padded, bf16 RGBx: .x=r|g<<16, .y=b)
//   [+PACK_TOTAL*8 ..)     uint2 packed0[NPIX]        (frm0, bf16 RGBx)
//   [+NPIX*8 ..)           float partials[UNSUP2_BLOCKS]
// fallback (no pack): partials at ws+16 floats

__global__ __launch_bounds__(256)
void repack_kp_kernel(const float* __restrict__ frm1, const float* __restrict__ frm0,
                      const float* __restrict__ kps, const float* __restrict__ pf,
                      float* __restrict__ ws, uint2* __restrict__ packed1,
                      uint2* __restrict__ packed0, int do_pack) {
    int g = blockIdx.x * 256 + threadIdx.x;
    if (do_pack) {
        if (g < PACK_TOTAL) {
            int b = g / PHW;
            int r = g - b * PHW;
            int py = r / PW;
            int px = r - py * PW;
            int x = px - 1, y = py - 1;
            uint2 v = make_uint2(0u, 0u);
            if (x >= 0 && x < NW && y >= 0 && y < NH) {
                const float* s = frm1 + (size_t)b * 3 * HW + y * NW + x;
                v.x = f2bf(s[0]) | (f2bf(s[HW]) << 16);
                v.y = f2bf(s[2 * HW]);
            }
            packed1[g] = v;
        }
        if (g < NPIX) {
            int b = g / HW;
            int o = g - b * HW;
            const float* s = frm0 + (size_t)b * 3 * HW + o;
            packed0[g] = make_uint2(f2bf(s[0]) | (f2bf(s[HW]) << 16), f2bf(s[2 * HW]));
        }
    }
    if (blockIdx.x == 0) {
        int t = threadIdx.x;
        // ---- keypoint supervised loss (sparse: <= 272 points, fp32 exact) ----
        __shared__ int cnt;
        __shared__ int ebase[NB * NJ];
        __shared__ float edx[NB * NJ], edy[NB * NJ];
        if (t == 0) cnt = 0;
        __syncthreads();
        for (int q = t; q < NB * NJ; q += 256) {
            int b = q / NJ, j = q - b * NJ;
            const float* k0 = kps + ((b * 2 + 0) * NJ + j) * 2;
            const float* k1 = kps + ((b * 2 + 1) * NJ + j) * 2;
            float x0 = k0[0], y0 = k0[1], x1 = k1[0], y1 = k1[1];
            bool valid = x0 >= 0.f && y0 >= 0.f && x1 >= 0.f && y1 >= 0.f &&
                         x0 < (float)NW && y0 < (float)NH &&
                         x1 < (float)NW && y1 < (float)NH;
            float dx = x1 - x0, dy = y1 - y0;
            if (valid && (dx != 0.f || dy != 0.f)) {
                int s = atomicAdd(&cnt, 1);
                ebase[s] = (b * 2) * HW + (int)floorf(y0) * NW + (int)floorf(x0);
                edx[s] = dx; edy[s] = dy;
            }
        }
        __syncthreads();
        int n = cnt;
        float local = 0.f;
        for (int q = t; q < n * NF; q += 256) {
            int e = q / NF, i = q - e * NF;
            float wt = (i == 0) ? 0.4096f : (i == 1) ? 0.512f :
                       (i == 2) ? 0.64f  : (i == 3) ? 0.8f   : 1.0f;
            int off = ebase[e] + i * (NB * 2 * HW);
            float ex = pf[off] - edx[e];
            float ey = pf[off + HW] - edy[e];
            local += wt * sqrtf(fmaf(ex, ex, ey * ey));
        }
        for (int o = 32; o > 0; o >>= 1) local += __shfl_down(local, o, 64);
        __shared__ float ssum[4];
        int lane = t & 63, wid = t >> 6;
        if (lane == 0) ssum[wid] = local;
        __syncthreads();
        if (t == 0) {
            ws[0] = ssum[0] + ssum[1] + ssum[2] + ssum[3];
            ws[1] = (float)n;
        }
    }
}

// Thread = 2 adjacent pixels at one level: two INDEPENDENT tap chains (MLP x2),
// vectorized flow/frm0 loads (VMEM instrs/item 13 -> 7.5), bf16 taps (8 B).
// Item order: w fastest, then level i, then b, h (L2 reuse across the 5 levels).
// No atomics/fences in this kernel (round-5 lesson).
__global__ __launch_bounds__(256, 8)
void unsup2_kernel(const float* __restrict__ pf, const uint2* __restrict__ packed1,
                   const uint2* __restrict__ packed0, float* __restrict__ partials) {
    const int idx = blockIdx.x * 256 + threadIdx.x;
    const int w2 = idx % (NW / 2);
    int q = idx / (NW / 2);
    const int i = q % NF;
    q = q / NF;
    const int b = q & (NB - 1);
    const int h = q >> 4;
    const int w0 = w2 * 2;
    const int off = h * NW + w0;
    const float SC = (float)(NW - 1) / (float)NW;

    // frm0: both pixels' RGB in ONE 16 B load (pixel index even -> 16B aligned)
    const uint4 f0 = *reinterpret_cast<const uint4*>(packed0 + (size_t)b * HW + off);

    // flow + neighbors (vector loads, 8B aligned; zero-pad at edges)
    const float* fb = pf + (size_t)((i * NB + b) * 2) * HW + off;
    const float2 fxv = *(const float2*)fb;
    const float2 fyv = *(const float2*)(fb + HW);
    float2 dnx = make_float2(0.f, 0.f), dny = make_float2(0.f, 0.f);
    if (h < NH - 1) { dnx = *(const float2*)(fb + NW); dny = *(const float2*)(fb + NW + HW); }
    float rtx1 = 0.f, rty1 = 0.f;
    if (w0 + 2 < NW) { rtx1 = fb[2]; rty1 = fb[HW + 2]; }

    const uint2* pk = packed1 + (size_t)b * PHW;
    float phot0, phot1, smooth0, smooth1;

    // ---- pixel 0 (right neighbor = pixel 1, in-register) ----
    {
        float fx = fxv.x, fy = fyv.x;
        smooth0 = charb(fx - dnx.x) + charb(fy - dny.x) +
                  charb(fx - fxv.y) + charb(fy - fyv.y);
        float xp = (fx + (float)w0) * SC;
        float yp = (fy + (float)h) * SC;
        xp = fminf(fmaxf(xp, -1.0f), 384.0f);
        yp = fminf(fmaxf(yp, -1.0f), 384.0f);
        float x0f = floorf(xp), y0f = floorf(yp);
        float wx1 = xp - x0f, wx0 = 1.f - wx1;
        float wy1 = yp - y0f, wy0 = 1.f - wy1;
        int p = ((int)y0f + 1) * PW + ((int)x0f + 1);
        uint2 t00 = pk[p], t10 = pk[p + 1], t01 = pk[p + PW], t11 = pk[p + PW + 1];
        float w00 = wx0 * wy0, w10 = wx1 * wy0, w01 = wx0 * wy1, w11 = wx1 * wy1;
        float s0 = w00 * bflo(t00.x) + w10 * bflo(t10.x) + w01 * bflo(t01.x) + w11 * bflo(t11.x);
        float s1 = w00 * bfhi(t00.x) + w10 * bfhi(t10.x) + w01 * bfhi(t01.x) + w11 * bfhi(t11.x);
        float s2 = w00 * bflo(t00.y) + w10 * bflo(t10.y) + w01 * bflo(t01.y) + w11 * bflo(t11.y);
        phot0 = charb(s0 - bflo(f0.x)) + charb(s1 - bfhi(f0.x)) + charb(s2 - bflo(f0.y));
    }
    // ---- pixel 1 (right neighbor loaded / zero at row end) ----
    {
        float fx = fxv.y, fy = fyv.y;
        smooth1 = charb(fx - dnx.y) + charb(fy - dny.y) +
                  charb(fx - rtx1) + charb(fy - rty1);
        float xp = (fx + (float)(w0 + 1)) * SC;
        float yp = (fy + (float)h) * SC;
        xp = fminf(fmaxf(xp, -1.0f), 384.0f);
        yp = fminf(fmaxf(yp, -1.0f), 384.0f);
        float x0f = floorf(xp), y0f = floorf(yp);
        float wx1 = xp - x0f, wx0 = 1.f - wx1;
        float wy1 = yp - y0f, wy0 = 1.f - wy1;
        int p = ((int)y0f + 1) * PW + ((int)x0f + 1);
        uint2 t00 = pk[p], t10 = pk[p + 1], t01 = pk[p + PW], t11 = pk[p + PW + 1];
        float w00 = wx0 * wy0, w10 = wx1 * wy0, w01 = wx0 * wy1, w11 = wx1 * wy1;
        float s0 = w00 * bflo(t00.x) + w10 * bflo(t10.x) + w01 * bflo(t01.x) + w11 * bflo(t11.x);
        float s1 = w00 * bfhi(t00.x) + w10 * bfhi(t10.x) + w01 * bfhi(t01.x) + w11 * bfhi(t11.x);
        float s2 = w00 * bflo(t00.y) + w10 * bflo(t10.y) + w01 * bflo(t01.y) + w11 * bflo(t11.y);
        phot1 = charb(s0 - bflo(f0.z)) + charb(s1 - bfhi(f0.z)) + charb(s2 - bflo(f0.w));
    }

    float wt = (i == 0) ? 0.4096f : (i == 1) ? 0.512f :
               (i == 2) ? 0.64f  : (i == 3) ? 0.8f   : 1.0f;
    float local = wt * fmaf(phot0 + phot1, (1.f / 3.f), (smooth0 + smooth1) * 0.5f);

    // block reduce (256 threads = 4 waves) -> per-block partial (no atomics)
    for (int o = 32; o > 0; o >>= 1) local += __shfl_down(local, o, 64);
    __shared__ float ssum[4];
    int lane = threadIdx.x & 63, wid = threadIdx.x >> 6;
    if (lane == 0) ssum[wid] = local;
    __syncthreads();
    if (threadIdx.x == 0) {
        partials[blockIdx.x] = ssum[0] + ssum[1] + ssum[2] + ssum[3];
    }
}

// Fallback (ws too small): round-9 planar single-item kernel, fp32 exact
__global__ __launch_bounds__(256, 8)
void unsup1_kernel(const float* __restrict__ pf, const float* __restrict__ frm0,
                   const float* __restrict__ frm1, float* __restrict__ partials) {
    const int idx = blockIdx.x * 256 + threadIdx.x;
    const int w = idx % NW;
    int q = idx / NW;
    const int i = q % NF;
    q = q / NF;
    const int b = q & (NB - 1);
    const int h = q >> 4;
    const int off = h * NW + w;
    const float SC = (float)(NW - 1) / (float)NW;
    const float* f0b = frm0 + b * 3 * HW + off;
    const float c0 = f0b[0], c1 = f0b[HW], c2 = f0b[2 * HW];
    const float* fb = pf + (size_t)((i * NB + b) * 2) * HW + off;
    const float fx = fb[0], fy = fb[HW];
    float dnx = 0.f, dny = 0.f, rtx = 0.f, rty = 0.f;
    if (h < NH - 1) { dnx = fb[NW]; dny = fb[NW + HW]; }
    if (w < NW - 1) { rtx = fb[1];  rty = fb[HW + 1]; }
    float smooth = charb(fx - dnx) + charb(fy - dny) + charb(fx - rtx) + charb(fy - rty);
    float xp = (fx + (float)w) * SC, yp = (fy + (float)h) * SC;
    float x0f = floorf(xp), y0f = floorf(yp);
    float wx1 = xp - x0f, wx0 = 1.f - wx1, wy1 = yp - y0f, wy0 = 1.f - wy1;
    bool vx0 = (x0f >= 0.f) && (x0f <= (float)(NW - 1));
    bool vx1 = (x0f >= -1.f) && (x0f <= (float)(NW - 2));
    bool vy0 = (y0f >= 0.f) && (y0f <= (float)(NH - 1));
    bool vy1 = (y0f >= -1.f) && (y0f <= (float)(NH - 2));
    float m00 = (vx0 && vy0) ? wx0 * wy0 : 0.f;
    float m10 = (vx1 && vy0) ? wx1 * wy0 : 0.f;
    float m01 = (vx0 && vy1) ? wx0 * wy1 : 0.f;
    float m11 = (vx1 && vy1) ? wx1 * wy1 : 0.f;
    int x0i = min(max((int)x0f, 0), NW - 1);
    int y0i = min(max((int)y0f, 0), NH - 1);
    int x1i = min(x0i + 1, NW - 1);
    int y1i = min(y0i + 1, NH - 1);
    const float* img = frm1 + b * 3 * HW;
    int i00 = y0i * NW + x0i, i10 = y0i * NW + x1i;
    int i01 = y1i * NW + x0i, i11 = y1i * NW + x1i;
    float s0 = m00 * img[i00] + m10 * img[i10] + m01 * img[i01] + m11 * img[i11];
    float s1 = m00 * img[HW + i00] + m10 * img[HW + i10] + m01 * img[HW + i01] + m11 * img[HW + i11];
    float s2 = m00 * img[2 * HW + i00] + m10 * img[2 * HW + i10] + m01 * img[2 * HW + i01] + m11 * img[2 * HW + i11];
    float phot = charb(s0 - c0) + charb(s1 - c1) + charb(s2 - c2);
    float wt = (i == 0) ? 0.4096f : (i == 1) ? 0.512f :
               (i == 2) ? 0.64f  : (i == 3) ? 0.8f   : 1.0f;
    float local = wt * fmaf(phot, (1.f / 3.f), smooth * 0.5f);
    for (int o = 32; o > 0; o >>= 1) local += __shfl_down(local, o, 64);
    __shared__ float ssum[4];
    int lane = threadIdx.x & 63, wid = threadIdx.x >> 6;
    if (lane == 0) ssum[wid] = local;
    __syncthreads();
    if (threadIdx.x == 0) partials[blockIdx.x] = ssum[0] + ssum[1] + ssum[2] + ssum[3];
}

__global__ __launch_bounds__(1024)
void final_kernel(const float* __restrict__ ws, const float* __restrict__ partials,
                  float* __restrict__ out, int nparts) {
    float local = 0.f;
    for (int q = threadIdx.x; q < nparts; q += 1024) local += partials[q];
    for (int o = 32; o > 0; o >>= 1) local += __shfl_down(local, o, 64);
    __shared__ float ssum[16];
    int lane = threadIdx.x & 63, wid = threadIdx.x >> 6;
    if (lane == 0) ssum[wid] = local;
    __syncthreads();
    if (threadIdx.x == 0) {
        float uns = 0.f;
        #pragma unroll
        for (int k = 0; k < 16; ++k) uns += ssum[k];
        float denom = fmaxf(ws[1], 1.f);
        out[0] = uns * (1.f / (float)NB) + ws[0] / denom;
    }
}

extern "C" void kernel_launch(void* const* d_in, const int* in_sizes, int n_in,
                              void* d_out, int out_size, void* d_ws, size_t ws_size,
                              hipStream_t stream) {
    const float* pf   = (const float*)d_in[0];  // (5,16,2,384,384)
    const float* kps  = (const float*)d_in[1];  // (16,2,17,2)
    const float* frm0 = (const float*)d_in[2];  // (16,3,384,384)
    const float* frm1 = (const float*)d_in[3];  // (16,3,384,384)
    float* out = (float*)d_out;
    float* ws  = (float*)d_ws;

    char* base = (char*)d_ws;
    uint2* packed1 = (uint2*)(base + 64);
    uint2* packed0 = (uint2*)(base + 64 + (size_t)PACK_TOTAL * 8);
    float* partials2 = (float*)(base + 64 + (size_t)PACK_TOTAL * 8 + (size_t)NPIX * 8);

    const size_t need = 64 + (size_t)PACK_TOTAL * 8 + (size_t)NPIX * 8 +
                        (size_t)UNSUP2_BLOCKS * 4;
    if (ws_size >= need) {
        repack_kp_kernel<<<(PACK_TOTAL + 255) / 256, 256, 0, stream>>>(
            frm1, frm0, kps, pf, ws, packed1, packed0, 1);
        unsup2_kernel<<<UNSUP2_BLOCKS, 256, 0, stream>>>(pf, packed1, packed0, partials2);
        final_kernel<<<1, 1024, 0, stream>>>(ws, partials2, out, UNSUP2_BLOCKS);
    } else {
        float* partials1 = ws + 16;
        repack_kp_kernel<<<1, 256, 0, stream>>>(frm1, frm0, kps, pf, ws,
                                                packed1, packed0, 0);
        unsup1_kernel<<<UNSUP1_BLOCKS, 256, 0, stream>>>(pf, frm0, frm1, partials1);
        final_kernel<<<1, 1024, 0, stream>>>(ws, partials1, out, UNSUP1_BLOCKS);
    }
}

// Round 13
// 254.417 us; speedup vs baseline: 6.8344x; 1.0756x over previous
//
#include <hip/hip_runtime.h>

// Problem constants: N=5, B=16, H=W=384, J=17
#define NF 5
#define NB 16
#define NH 384
#define NW 384
#define NJ 17
#define HW (NH * NW)
#define PW (NW + 3)                   // padded cols: x = -1 .. 385
#define PH (NH + 3)
#define PHW (PH * PW)                 // 149769
#define NPIX (NB * HW)                // 2,359,296
#define PACK_TOTAL (NB * PHW)         // 2,396,304
#define NTHREADS4 (NF * NB * NH * (NW / 4))  // 2,949,120
#define UNSUP4_BLOCKS (NTHREADS4 / 256)      // 11520
#define UNSUP1_BLOCKS ((NF * NB * HW) / 256) // 46080 (fallback)

// fast charbonnier: (x^2 + 1e-18)^0.25 via raw v_sqrt_f32 (~1 ulp; threshold 2% rel)
__device__ __forceinline__ float charb(float x) {
    return __builtin_amdgcn_sqrtf(__builtin_amdgcn_sqrtf(fmaf(x, x, 1e-18f)));
}
// f32 -> bf16 (RNE), values are finite [0,1): no NaN handling needed
__device__ __forceinline__ unsigned int f2bf(float f) {
    unsigned int x = __builtin_bit_cast(unsigned int, f);
    x += 0x7FFFu + ((x >> 16) & 1u);
    return x >> 16;
}
__device__ __forceinline__ float bflo(unsigned int u) {
    return __builtin_bit_cast(float, u << 16);
}
__device__ __forceinline__ float bfhi(unsigned int u) {
    return __builtin_bit_cast(float, u & 0xFFFF0000u);
}

// ws layout (bytes):
//   [0..63]   float ws[0]=sup_sum, ws[1]=denom
//   [64 ..)                uint2 packed1[PACK_TOTAL]  (frm1 padded, bf16 RGBx)
//   [+PACK_TOTAL*8 ..)     uint2 packed0[NPIX]        (frm0, bf16 RGBx)
//   [+NPIX*8 ..)           float partials[UNSUP4_BLOCKS]
// fallback (no pack): partials at ws+16 floats

__global__ __launch_bounds__(256)
void repack_kp_kernel(const float* __restrict__ frm1, const float* __restrict__ frm0,
                      const float* __restrict__ kps, const float* __restrict__ pf,
                      float* __restrict__ ws, uint2* __restrict__ packed1,
                      uint2* __restrict__ packed0, int do_pack) {
    int g = blockIdx.x * 256 + threadIdx.x;
    if (do_pack) {
        if (g < PACK_TOTAL) {
            int b = g / PHW;
            int r = g - b * PHW;
            int py = r / PW;
            int px = r - py * PW;
            int x = px - 1, y = py - 1;
            uint2 v = make_uint2(0u, 0u);
            if (x >= 0 && x < NW && y >= 0 && y < NH) {
                const float* s = frm1 + (size_t)b * 3 * HW + y * NW + x;
                v.x = f2bf(s[0]) | (f2bf(s[HW]) << 16);
                v.y = f2bf(s[2 * HW]);
            }
            packed1[g] = v;
        }
        if (g < NPIX) {
            int b = g / HW;
            int o = g - b * HW;
            const float* s = frm0 + (size_t)b * 3 * HW + o;
            packed0[g] = make_uint2(f2bf(s[0]) | (f2bf(s[HW]) << 16), f2bf(s[2 * HW]));
        }
    }
    if (blockIdx.x == 0) {
        int t = threadIdx.x;
        // ---- keypoint supervised loss (sparse: <= 272 points, fp32 exact) ----
        __shared__ int cnt;
        __shared__ int ebase[NB * NJ];
        __shared__ float edx[NB * NJ], edy[NB * NJ];
        if (t == 0) cnt = 0;
        __syncthreads();
        for (int q = t; q < NB * NJ; q += 256) {
            int b = q / NJ, j = q - b * NJ;
            const float* k0 = kps + ((b * 2 + 0) * NJ + j) * 2;
            const float* k1 = kps + ((b * 2 + 1) * NJ + j) * 2;
            float x0 = k0[0], y0 = k0[1], x1 = k1[0], y1 = k1[1];
            bool valid = x0 >= 0.f && y0 >= 0.f && x1 >= 0.f && y1 >= 0.f &&
                         x0 < (float)NW && y0 < (float)NH &&
                         x1 < (float)NW && y1 < (float)NH;
            float dx = x1 - x0, dy = y1 - y0;
            if (valid && (dx != 0.f || dy != 0.f)) {
                int s = atomicAdd(&cnt, 1);
                ebase[s] = (b * 2) * HW + (int)floorf(y0) * NW + (int)floorf(x0);
                edx[s] = dx; edy[s] = dy;
            }
        }
        __syncthreads();
        int n = cnt;
        float local = 0.f;
        for (int q = t; q < n * NF; q += 256) {
            int e = q / NF, i = q - e * NF;
            float wt = (i == 0) ? 0.4096f : (i == 1) ? 0.512f :
                       (i == 2) ? 0.64f  : (i == 3) ? 0.8f   : 1.0f;
            int off = ebase[e] + i * (NB * 2 * HW);
            float ex = pf[off] - edx[e];
            float ey = pf[off + HW] - edy[e];
            local += wt * sqrtf(fmaf(ex, ex, ey * ey));
        }
        for (int o = 32; o > 0; o >>= 1) local += __shfl_down(local, o, 64);
        __shared__ float ssum[4];
        int lane = t & 63, wid = t >> 6;
        if (lane == 0) ssum[wid] = local;
        __syncthreads();
        if (t == 0) {
            ws[0] = ssum[0] + ssum[1] + ssum[2] + ssum[3];
            ws[1] = (float)n;
        }
    }
}

// Thread = 4 adjacent pixels at one level. Source is explicitly phased:
//   (1) issue ALL loads (flow float4s, frm0 2x uint4, 16 tap uint2s into
//       fully-unrolled register arrays)  (2) smoothness VALU (uses only flow,
//       overlaps tap latency)  (3) bilinear+charb.
// 16 independent in-flight tap loads per thread = 4x round-11 MLP (round-11
// lesson: VGPR=24 proved the compiler serialized the 2-pixel version).
// __launch_bounds__(256,6): 85-VGPR cap, occupancy floor 75%.
__global__ __launch_bounds__(256, 6)
void unsup4_kernel(const float* __restrict__ pf, const uint2* __restrict__ packed1,
                   const uint2* __restrict__ packed0, float* __restrict__ partials) {
    const int idx = blockIdx.x * 256 + threadIdx.x;
    const int w4 = idx % (NW / 4);
    int q = idx / (NW / 4);
    const int i = q % NF;
    q = q / NF;
    const int b = q & (NB - 1);
    const int h = q >> 4;
    const int w0 = w4 * 4;
    const int off = h * NW + w0;
    const float SC = (float)(NW - 1) / (float)NW;

    // ---- phase 1: issue all loads ----
    const uint2* p0 = packed0 + (size_t)b * HW + off;
    const uint4 f0lo = *reinterpret_cast<const uint4*>(p0);      // px0,1 RGB
    const uint4 f0hi = *reinterpret_cast<const uint4*>(p0 + 2);  // px2,3 RGB

    const float* fb = pf + (size_t)((i * NB + b) * 2) * HW + off;
    const float4 fx4 = *(const float4*)fb;
    const float4 fy4 = *(const float4*)(fb + HW);
    float4 dnx4 = make_float4(0.f, 0.f, 0.f, 0.f);
    float4 dny4 = make_float4(0.f, 0.f, 0.f, 0.f);
    if (h < NH - 1) {
        dnx4 = *(const float4*)(fb + NW);
        dny4 = *(const float4*)(fb + NW + HW);
    }
    float rtx = 0.f, rty = 0.f;
    if (w0 + 4 < NW) { rtx = fb[4]; rty = fb[HW + 4]; }

    const float fxa[4] = {fx4.x, fx4.y, fx4.z, fx4.w};
    const float fya[4] = {fy4.x, fy4.y, fy4.z, fy4.w};

    // tap addresses + bilinear weights (depends only on flow)
    const uint2* pk = packed1 + (size_t)b * PHW;
    int pbase[4];
    float wx1a[4], wy1a[4];
#pragma unroll
    for (int k = 0; k < 4; ++k) {
        float xp = (fxa[k] + (float)(w0 + k)) * SC;
        float yp = (fya[k] + (float)h) * SC;
        xp = fminf(fmaxf(xp, -1.0f), 384.0f);
        yp = fminf(fmaxf(yp, -1.0f), 384.0f);
        float x0f = floorf(xp), y0f = floorf(yp);
        wx1a[k] = xp - x0f;
        wy1a[k] = yp - y0f;
        pbase[k] = ((int)y0f + 1) * PW + ((int)x0f + 1);
    }
    // 16 independent tap loads, all in flight together
    uint2 t00[4], t10[4], t01[4], t11[4];
#pragma unroll
    for (int k = 0; k < 4; ++k) {
        t00[k] = pk[pbase[k]];
        t10[k] = pk[pbase[k] + 1];
        t01[k] = pk[pbase[k] + PW];
        t11[k] = pk[pbase[k] + PW + 1];
    }

    // ---- phase 2: smoothness (flow-only VALU, overlaps tap latency) ----
    const float rxa[4] = {fx4.y, fx4.z, fx4.w, rtx};
    const float rya[4] = {fy4.y, fy4.z, fy4.w, rty};
    const float dnxa[4] = {dnx4.x, dnx4.y, dnx4.z, dnx4.w};
    const float dnya[4] = {dny4.x, dny4.y, dny4.z, dny4.w};
    float smooth = 0.f;
#pragma unroll
    for (int k = 0; k < 4; ++k) {
        smooth += charb(fxa[k] - dnxa[k]) + charb(fya[k] - dnya[k]) +
                  charb(fxa[k] - rxa[k]) + charb(fya[k] - rya[k]);
    }

    // ---- phase 3: bilinear + photometric charb ----
    const unsigned int c01a[4] = {f0lo.x, f0lo.z, f0hi.x, f0hi.z};  // r|g<<16
    const unsigned int c2a[4]  = {f0lo.y, f0lo.w, f0hi.y, f0hi.w};  // b
    float phot = 0.f;
#pragma unroll
    for (int k = 0; k < 4; ++k) {
        float wx1 = wx1a[k], wx0 = 1.f - wx1;
        float wy1 = wy1a[k], wy0 = 1.f - wy1;
        float w00 = wx0 * wy0, w10 = wx1 * wy0, w01 = wx0 * wy1, w11 = wx1 * wy1;
        float s0 = w00 * bflo(t00[k].x) + w10 * bflo(t10[k].x) +
                   w01 * bflo(t01[k].x) + w11 * bflo(t11[k].x);
        float s1 = w00 * bfhi(t00[k].x) + w10 * bfhi(t10[k].x) +
                   w01 * bfhi(t01[k].x) + w11 * bfhi(t11[k].x);
        float s2 = w00 * bflo(t00[k].y) + w10 * bflo(t10[k].y) +
                   w01 * bflo(t01[k].y) + w11 * bflo(t11[k].y);
        phot += charb(s0 - bflo(c01a[k])) + charb(s1 - bfhi(c01a[k])) +
                charb(s2 - bflo(c2a[k]));
    }

    float wt = (i == 0) ? 0.4096f : (i == 1) ? 0.512f :
               (i == 2) ? 0.64f  : (i == 3) ? 0.8f   : 1.0f;
    float local = wt * fmaf(phot, (1.f / 3.f), smooth * 0.5f);

    // block reduce (256 threads = 4 waves) -> per-block partial (no atomics)
    for (int o = 32; o > 0; o >>= 1) local += __shfl_down(local, o, 64);
    __shared__ float ssum[4];
    int lane = threadIdx.x & 63, wid = threadIdx.x >> 6;
    if (lane == 0) ssum[wid] = local;
    __syncthreads();
    if (threadIdx.x == 0) {
        partials[blockIdx.x] = ssum[0] + ssum[1] + ssum[2] + ssum[3];
    }
}

// Fallback (ws too small): round-9 planar single-item kernel, fp32 exact
__global__ __launch_bounds__(256, 8)
void unsup1_kernel(const float* __restrict__ pf, const float* __restrict__ frm0,
                   const float* __restrict__ frm1, float* __restrict__ partials) {
    const int idx = blockIdx.x * 256 + threadIdx.x;
    const int w = idx % NW;
    int q = idx / NW;
    const int i = q % NF;
    q = q / NF;
    const int b = q & (NB - 1);
    const int h = q >> 4;
    const int off = h * NW + w;
    const float SC = (float)(NW - 1) / (float)NW;
    const float* f0b = frm0 + b * 3 * HW + off;
    const float c0 = f0b[0], c1 = f0b[HW], c2 = f0b[2 * HW];
    const float* fb = pf + (size_t)((i * NB + b) * 2) * HW + off;
    const float fx = fb[0], fy = fb[HW];
    float dnx = 0.f, dny = 0.f, rtx = 0.f, rty = 0.f;
    if (h < NH - 1) { dnx = fb[NW]; dny = fb[NW + HW]; }
    if (w < NW - 1) { rtx = fb[1];  rty = fb[HW + 1]; }
    float smooth = charb(fx - dnx) + charb(fy - dny) + charb(fx - rtx) + charb(fy - rty);
    float xp = (fx + (float)w) * SC, yp = (fy + (float)h) * SC;
    float x0f = floorf(xp), y0f = floorf(yp);
    float wx1 = xp - x0f, wx0 = 1.f - wx1, wy1 = yp - y0f, wy0 = 1.f - wy1;
    bool vx0 = (x0f >= 0.f) && (x0f <= (float)(NW - 1));
    bool vx1 = (x0f >= -1.f) && (x0f <= (float)(NW - 2));
    bool vy0 = (y0f >= 0.f) && (y0f <= (float)(NH - 1));
    bool vy1 = (y0f >= -1.f) && (y0f <= (float)(NH - 2));
    float m00 = (vx0 && vy0) ? wx0 * wy0 : 0.f;
    float m10 = (vx1 && vy0) ? wx1 * wy0 : 0.f;
    float m01 = (vx0 && vy1) ? wx0 * wy1 : 0.f;
    float m11 = (vx1 && vy1) ? wx1 * wy1 : 0.f;
    int x0i = min(max((int)x0f, 0), NW - 1);
    int y0i = min(max((int)y0f, 0), NH - 1);
    int x1i = min(x0i + 1, NW - 1);
    int y1i = min(y0i + 1, NH - 1);
    const float* img = frm1 + b * 3 * HW;
    int i00 = y0i * NW + x0i, i10 = y0i * NW + x1i;
    int i01 = y1i * NW + x0i, i11 = y1i * NW + x1i;
    float s0 = m00 * img[i00] + m10 * img[i10] + m01 * img[i01] + m11 * img[i11];
    float s1 = m00 * img[HW + i00] + m10 * img[HW + i10] + m01 * img[HW + i01] + m11 * img[HW + i11];
    float s2 = m00 * img[2 * HW + i00] + m10 * img[2 * HW + i10] + m01 * img[2 * HW + i01] + m11 * img[2 * HW + i11];
    float phot = charb(s0 - c0) + charb(s1 - c1) + charb(s2 - c2);
    float wt = (i == 0) ? 0.4096f : (i == 1) ? 0.512f :
               (i == 2) ? 0.64f  : (i == 3) ? 0.8f   : 1.0f;
    float local = wt * fmaf(phot, (1.f / 3.f), smooth * 0.5f);
    for (int o = 32; o > 0; o >>= 1) local += __shfl_down(local, o, 64);
    __shared__ float ssum[4];
    int lane = threadIdx.x & 63, wid = threadIdx.x >> 6;
    if (lane == 0) ssum[wid] = local;
    __syncthreads();
    if (threadIdx.x == 0) partials[blockIdx.x] = ssum[0] + ssum[1] + ssum[2] + ssum[3];
}

__global__ __launch_bounds__(1024)
void final_kernel(const float* __restrict__ ws, const float* __restrict__ partials,
                  float* __restrict__ out, int nparts) {
    float local = 0.f;
    for (int q = threadIdx.x; q < nparts; q += 1024) local += partials[q];
    for (int o = 32; o > 0; o >>= 1) local += __shfl_down(local, o, 64);
    __shared__ float ssum[16];
    int lane = threadIdx.x & 63, wid = threadIdx.x >> 6;
    if (lane == 0) ssum[wid] = local;
    __syncthreads();
    if (threadIdx.x == 0) {
        float uns = 0.f;
        #pragma unroll
        for (int k = 0; k < 16; ++k) uns += ssum[k];
        float denom = fmaxf(ws[1], 1.f);
        out[0] = uns * (1.f / (float)NB) + ws[0] / denom;
    }
}

extern "C" void kernel_launch(void* const* d_in, const int* in_sizes, int n_in,
                              void* d_out, int out_size, void* d_ws, size_t ws_size,
                              hipStream_t stream) {
    const float* pf   = (const float*)d_in[0];  // (5,16,2,384,384)
    const float* kps  = (const float*)d_in[1];  // (16,2,17,2)
    const float* frm0 = (const float*)d_in[2];  // (16,3,384,384)
    const float* frm1 = (const float*)d_in[3];  // (16,3,384,384)
    float* out = (float*)d_out;
    float* ws  = (float*)d_ws;

    char* base = (char*)d_ws;
    uint2* packed1 = (uint2*)(base + 64);
    uint2* packed0 = (uint2*)(base + 64 + (size_t)PACK_TOTAL * 8);
    float* partials4 = (float*)(base + 64 + (size_t)PACK_TOTAL * 8 + (size_t)NPIX * 8);

    const size_t need = 64 + (size_t)PACK_TOTAL * 8 + (size_t)NPIX * 8 +
                        (size_t)UNSUP4_BLOCKS * 4;
    if (ws_size >= need) {
        repack_kp_kernel<<<(PACK_TOTAL + 255) / 256, 256, 0, stream>>>(
            frm1, frm0, kps, pf, ws, packed1, packed0, 1);
        unsup4_kernel<<<UNSUP4_BLOCKS, 256, 0, stream>>>(pf, packed1, packed0, partials4);
        final_kernel<<<1, 1024, 0, stream>>>(ws, partials4, out, UNSUP4_BLOCKS);
    } else {
        float* partials1 = ws + 16;
        repack_kp_kernel<<<1, 256, 0, stream>>>(frm1, frm0, kps, pf, ws,
                                                packed1, packed0, 0);
        unsup1_kernel<<<UNSUP1_BLOCKS, 256, 0, stream>>>(pf, frm0, frm1, partials1);
        final_kernel<<<1, 1024, 0, stream>>>(ws, partials1, out, UNSUP1_BLOCKS);
    }
}

// Round 14
// 225.656 us; speedup vs baseline: 7.7055x; 1.1275x over previous
//
#include <hip/hip_runtime.h>

// Problem constants: N=5, B=16, H=W=384, J=17
#define NF 5
#define NB 16
#define NH 384
#define NW 384
#define NJ 17
#define HW (NH * NW)
#define PW (NW + 3)                   // padded cols: x = -1 .. 385
#define PH (NH + 3)
#define PHW (PH * PW)                 // 149769
#define NPIX (NB * HW)                // 2,359,296
#define PACK_TOTAL (NB * PHW)         // 2,396,304
#define NTHREADS4 (NF * NB * NH * (NW / 4))  // 2,949,120
#define UNSUP4_BLOCKS (NTHREADS4 / 256)      // 11520
#define UNSUP1_BLOCKS ((NF * NB * HW) / 256) // 46080 (fallback)

// fast charbonnier: (x^2 + 1e-18)^0.25 via raw v_sqrt_f32 (~1 ulp; threshold 2% rel)
__device__ __forceinline__ float charb(float x) {
    return __builtin_amdgcn_sqrtf(__builtin_amdgcn_sqrtf(fmaf(x, x, 1e-18f)));
}
// RGB in [0,1) -> 11/11/10-bit fixed point in one u32 (abs err <= 4.9e-4,
// 4-8x MORE accurate than the bf16 pack that already passed with absmax 0.0)
__device__ __forceinline__ unsigned int packrgb(float r, float g, float b) {
    unsigned int er = (unsigned int)fmaf(r, 2047.f, 0.5f);
    unsigned int eg = (unsigned int)fmaf(g, 2047.f, 0.5f);
    unsigned int eb = (unsigned int)fmaf(b, 1023.f, 0.5f);
    return er | (eg << 11) | (eb << 22);
}
__device__ __forceinline__ float upk_r(unsigned int u) {
    return (float)(u & 2047u) * (1.f / 2047.f);
}
__device__ __forceinline__ float upk_g(unsigned int u) {
    return (float)((u >> 11) & 2047u) * (1.f / 2047.f);
}
__device__ __forceinline__ float upk_b(unsigned int u) {
    return (float)(u >> 22) * (1.f / 1023.f);
}

// ws layout (bytes):
//   [0..63]   float ws[0]=sup_sum, ws[1]=denom
//   [64 ..)                uint packed1[PACK_TOTAL]  (frm1 padded, 11/11/10 RGB)
//   [+PACK_TOTAL*4 ..)     uint packed0[NPIX]        (frm0, 11/11/10 RGB)
//   [+NPIX*4 ..)           float partials[UNSUP4_BLOCKS]
// fallback (no pack): partials at ws+16 floats

__global__ __launch_bounds__(256)
void repack_kp_kernel(const float* __restrict__ frm1, const float* __restrict__ frm0,
                      const float* __restrict__ kps, const float* __restrict__ pf,
                      float* __restrict__ ws, unsigned int* __restrict__ packed1,
                      unsigned int* __restrict__ packed0, int do_pack) {
    int g = blockIdx.x * 256 + threadIdx.x;
    if (do_pack) {
        if (g < PACK_TOTAL) {
            int b = g / PHW;
            int r = g - b * PHW;
            int py = r / PW;
            int px = r - py * PW;
            int x = px - 1, y = py - 1;
            unsigned int v = 0u;
            if (x >= 0 && x < NW && y >= 0 && y < NH) {
                const float* s = frm1 + (size_t)b * 3 * HW + y * NW + x;
                v = packrgb(s[0], s[HW], s[2 * HW]);
            }
            packed1[g] = v;
        }
        if (g < NPIX) {
            int b = g / HW;
            int o = g - b * HW;
            const float* s = frm0 + (size_t)b * 3 * HW + o;
            packed0[g] = packrgb(s[0], s[HW], s[2 * HW]);
        }
    }
    if (blockIdx.x == 0) {
        int t = threadIdx.x;
        // ---- keypoint supervised loss (sparse: <= 272 points, fp32 exact) ----
        __shared__ int cnt;
        __shared__ int ebase[NB * NJ];
        __shared__ float edx[NB * NJ], edy[NB * NJ];
        if (t == 0) cnt = 0;
        __syncthreads();
        for (int q = t; q < NB * NJ; q += 256) {
            int b = q / NJ, j = q - b * NJ;
            const float* k0 = kps + ((b * 2 + 0) * NJ + j) * 2;
            const float* k1 = kps + ((b * 2 + 1) * NJ + j) * 2;
            float x0 = k0[0], y0 = k0[1], x1 = k1[0], y1 = k1[1];
            bool valid = x0 >= 0.f && y0 >= 0.f && x1 >= 0.f && y1 >= 0.f &&
                         x0 < (float)NW && y0 < (float)NH &&
                         x1 < (float)NW && y1 < (float)NH;
            float dx = x1 - x0, dy = y1 - y0;
            if (valid && (dx != 0.f || dy != 0.f)) {
                int s = atomicAdd(&cnt, 1);
                ebase[s] = (b * 2) * HW + (int)floorf(y0) * NW + (int)floorf(x0);
                edx[s] = dx; edy[s] = dy;
            }
        }
        __syncthreads();
        int n = cnt;
        float local = 0.f;
        for (int q = t; q < n * NF; q += 256) {
            int e = q / NF, i = q - e * NF;
            float wt = (i == 0) ? 0.4096f : (i == 1) ? 0.512f :
                       (i == 2) ? 0.64f  : (i == 3) ? 0.8f   : 1.0f;
            int off = ebase[e] + i * (NB * 2 * HW);
            float ex = pf[off] - edx[e];
            float ey = pf[off + HW] - edy[e];
            local += wt * sqrtf(fmaf(ex, ex, ey * ey));
        }
        for (int o = 32; o > 0; o >>= 1) local += __shfl_down(local, o, 64);
        __shared__ float ssum[4];
        int lane = t & 63, wid = t >> 6;
        if (lane == 0) ssum[wid] = local;
        __syncthreads();
        if (t == 0) {
            ws[0] = ssum[0] + ssum[1] + ssum[2] + ssum[3];
            ws[1] = (float)n;
        }
    }
}

// Thread = 4 adjacent pixels at one level, phased: (1) issue ALL loads — flow
// float4s, frm0 ONE uint4 (4px x 4B), 16 tap u32s into unrolled register
// arrays (16 VGPRs total: compiler can keep all in flight, unlike the 32-VGPR
// bf16 version where it kept ~8 -> VGPR=40)  (2) smoothness VALU overlaps tap
// latency  (3) decode + bilinear + charb.  4B taps ~halve the divergent
// gather's cacheline footprint (the measured TCP-transaction bottleneck).
__global__ __launch_bounds__(256, 6)
void unsup4_kernel(const float* __restrict__ pf, const unsigned int* __restrict__ packed1,
                   const unsigned int* __restrict__ packed0, float* __restrict__ partials) {
    const int idx = blockIdx.x * 256 + threadIdx.x;
    const int w4 = idx % (NW / 4);
    int q = idx / (NW / 4);
    const int i = q % NF;
    q = q / NF;
    const int b = q & (NB - 1);
    const int h = q >> 4;
    const int w0 = w4 * 4;
    const int off = h * NW + w0;
    const float SC = (float)(NW - 1) / (float)NW;

    // ---- phase 1: issue all loads ----
    const uint4 f0 = *reinterpret_cast<const uint4*>(packed0 + (size_t)b * HW + off);

    const float* fb = pf + (size_t)((i * NB + b) * 2) * HW + off;
    const float4 fx4 = *(const float4*)fb;
    const float4 fy4 = *(const float4*)(fb + HW);
    float4 dnx4 = make_float4(0.f, 0.f, 0.f, 0.f);
    float4 dny4 = make_float4(0.f, 0.f, 0.f, 0.f);
    if (h < NH - 1) {
        dnx4 = *(const float4*)(fb + NW);
        dny4 = *(const float4*)(fb + NW + HW);
    }
    float rtx = 0.f, rty = 0.f;
    if (w0 + 4 < NW) { rtx = fb[4]; rty = fb[HW + 4]; }

    const float fxa[4] = {fx4.x, fx4.y, fx4.z, fx4.w};
    const float fya[4] = {fy4.x, fy4.y, fy4.z, fy4.w};

    // tap addresses + bilinear weights (depend only on flow)
    const unsigned int* pk = packed1 + (size_t)b * PHW;
    int pbase[4];
    float wx1a[4], wy1a[4];
#pragma unroll
    for (int k = 0; k < 4; ++k) {
        float xp = (fxa[k] + (float)(w0 + k)) * SC;
        float yp = (fya[k] + (float)h) * SC;
        xp = fminf(fmaxf(xp, -1.0f), 384.0f);
        yp = fminf(fmaxf(yp, -1.0f), 384.0f);
        float x0f = floorf(xp), y0f = floorf(yp);
        wx1a[k] = xp - x0f;
        wy1a[k] = yp - y0f;
        pbase[k] = ((int)y0f + 1) * PW + ((int)x0f + 1);
    }
    // 16 independent 4B tap loads, all in flight together (16 VGPRs)
    unsigned int t00[4], t10[4], t01[4], t11[4];
#pragma unroll
    for (int k = 0; k < 4; ++k) {
        t00[k] = pk[pbase[k]];
        t10[k] = pk[pbase[k] + 1];
        t01[k] = pk[pbase[k] + PW];
        t11[k] = pk[pbase[k] + PW + 1];
    }

    // ---- phase 2: smoothness (flow-only VALU, overlaps tap latency) ----
    const float rxa[4] = {fx4.y, fx4.z, fx4.w, rtx};
    const float rya[4] = {fy4.y, fy4.z, fy4.w, rty};
    const float dnxa[4] = {dnx4.x, dnx4.y, dnx4.z, dnx4.w};
    const float dnya[4] = {dny4.x, dny4.y, dny4.z, dny4.w};
    float smooth = 0.f;
#pragma unroll
    for (int k = 0; k < 4; ++k) {
        smooth += charb(fxa[k] - dnxa[k]) + charb(fya[k] - dnya[k]) +
                  charb(fxa[k] - rxa[k]) + charb(fya[k] - rya[k]);
    }

    // ---- phase 3: decode + bilinear + photometric charb ----
    const unsigned int f0a[4] = {f0.x, f0.y, f0.z, f0.w};
    float phot = 0.f;
#pragma unroll
    for (int k = 0; k < 4; ++k) {
        float wx1 = wx1a[k], wx0 = 1.f - wx1;
        float wy1 = wy1a[k], wy0 = 1.f - wy1;
        float w00 = wx0 * wy0, w10 = wx1 * wy0, w01 = wx0 * wy1, w11 = wx1 * wy1;
        float s0 = w00 * upk_r(t00[k]) + w10 * upk_r(t10[k]) +
                   w01 * upk_r(t01[k]) + w11 * upk_r(t11[k]);
        float s1 = w00 * upk_g(t00[k]) + w10 * upk_g(t10[k]) +
                   w01 * upk_g(t01[k]) + w11 * upk_g(t11[k]);
        float s2 = w00 * upk_b(t00[k]) + w10 * upk_b(t10[k]) +
                   w01 * upk_b(t01[k]) + w11 * upk_b(t11[k]);
        phot += charb(s0 - upk_r(f0a[k])) + charb(s1 - upk_g(f0a[k])) +
                charb(s2 - upk_b(f0a[k]));
    }

    float wt = (i == 0) ? 0.4096f : (i == 1) ? 0.512f :
               (i == 2) ? 0.64f  : (i == 3) ? 0.8f   : 1.0f;
    float local = wt * fmaf(phot, (1.f / 3.f), smooth * 0.5f);

    // block reduce (256 threads = 4 waves) -> per-block partial (no atomics)
    for (int o = 32; o > 0; o >>= 1) local += __shfl_down(local, o, 64);
    __shared__ float ssum[4];
    int lane = threadIdx.x & 63, wid = threadIdx.x >> 6;
    if (lane == 0) ssum[wid] = local;
    __syncthreads();
    if (threadIdx.x == 0) {
        partials[blockIdx.x] = ssum[0] + ssum[1] + ssum[2] + ssum[3];
    }
}

// Fallback (ws too small): planar single-item kernel, fp32 exact
__global__ __launch_bounds__(256, 8)
void unsup1_kernel(const float* __restrict__ pf, const float* __restrict__ frm0,
                   const float* __restrict__ frm1, float* __restrict__ partials) {
    const int idx = blockIdx.x * 256 + threadIdx.x;
    const int w = idx % NW;
    int q = idx / NW;
    const int i = q % NF;
    q = q / NF;
    const int b = q & (NB - 1);
    const int h = q >> 4;
    const int off = h * NW + w;
    const float SC = (float)(NW - 1) / (float)NW;
    const float* f0b = frm0 + b * 3 * HW + off;
    const float c0 = f0b[0], c1 = f0b[HW], c2 = f0b[2 * HW];
    const float* fb = pf + (size_t)((i * NB + b) * 2) * HW + off;
    const float fx = fb[0], fy = fb[HW];
    float dnx = 0.f, dny = 0.f, rtx = 0.f, rty = 0.f;
    if (h < NH - 1) { dnx = fb[NW]; dny = fb[NW + HW]; }
    if (w < NW - 1) { rtx = fb[1];  rty = fb[HW + 1]; }
    float smooth = charb(fx - dnx) + charb(fy - dny) + charb(fx - rtx) + charb(fy - rty);
    float xp = (fx + (float)w) * SC, yp = (fy + (float)h) * SC;
    float x0f = floorf(xp), y0f = floorf(yp);
    float wx1 = xp - x0f, wx0 = 1.f - wx1, wy1 = yp - y0f, wy0 = 1.f - wy1;
    bool vx0 = (x0f >= 0.f) && (x0f <= (float)(NW - 1));
    bool vx1 = (x0f >= -1.f) && (x0f <= (float)(NW - 2));
    bool vy0 = (y0f >= 0.f) && (y0f <= (float)(NH - 1));
    bool vy1 = (y0f >= -1.f) && (y0f <= (float)(NH - 2));
    float m00 = (vx0 && vy0) ? wx0 * wy0 : 0.f;
    float m10 = (vx1 && vy0) ? wx1 * wy0 : 0.f;
    float m01 = (vx0 && vy1) ? wx0 * wy1 : 0.f;
    float m11 = (vx1 && vy1) ? wx1 * wy1 : 0.f;
    int x0i = min(max((int)x0f, 0), NW - 1);
    int y0i = min(max((int)y0f, 0), NH - 1);
    int x1i = min(x0i + 1, NW - 1);
    int y1i = min(y0i + 1, NH - 1);
    const float* img = frm1 + b * 3 * HW;
    int i00 = y0i * NW + x0i, i10 = y0i * NW + x1i;
    int i01 = y1i * NW + x0i, i11 = y1i * NW + x1i;
    float s0 = m00 * img[i00] + m10 * img[i10] + m01 * img[i01] + m11 * img[i11];
    float s1 = m00 * img[HW + i00] + m10 * img[HW + i10] + m01 * img[HW + i01] + m11 * img[HW + i11];
    float s2 = m00 * img[2 * HW + i00] + m10 * img[2 * HW + i10] + m01 * img[2 * HW + i01] + m11 * img[2 * HW + i11];
    float phot = charb(s0 - c0) + charb(s1 - c1) + charb(s2 - c2);
    float wt = (i == 0) ? 0.4096f : (i == 1) ? 0.512f :
               (i == 2) ? 0.64f  : (i == 3) ? 0.8f   : 1.0f;
    float local = wt * fmaf(phot, (1.f / 3.f), smooth * 0.5f);
    for (int o = 32; o > 0; o >>= 1) local += __shfl_down(local, o, 64);
    __shared__ float ssum[4];
    int lane = threadIdx.x & 63, wid = threadIdx.x >> 6;
    if (lane == 0) ssum[wid] = local;
    __syncthreads();
    if (threadIdx.x == 0) partials[blockIdx.x] = ssum[0] + ssum[1] + ssum[2] + ssum[3];
}

__global__ __launch_bounds__(1024)
void final_kernel(const float* __restrict__ ws, const float* __restrict__ partials,
                  float* __restrict__ out, int nparts) {
    float local = 0.f;
    for (int q = threadIdx.x; q < nparts; q += 1024) local += partials[q];
    for (int o = 32; o > 0; o >>= 1) local += __shfl_down(local, o, 64);
    __shared__ float ssum[16];
    int lane = threadIdx.x & 63, wid = threadIdx.x >> 6;
    if (lane == 0) ssum[wid] = local;
    __syncthreads();
    if (threadIdx.x == 0) {
        float uns = 0.f;
        #pragma unroll
        for (int k = 0; k < 16; ++k) uns += ssum[k];
        float denom = fmaxf(ws[1], 1.f);
        out[0] = uns * (1.f / (float)NB) + ws[0] / denom;
    }
}

extern "C" void kernel_launch(void* const* d_in, const int* in_sizes, int n_in,
                              void* d_out, int out_size, void* d_ws, size_t ws_size,
                              hipStream_t stream) {
    const float* pf   = (const float*)d_in[0];  // (5,16,2,384,384)
    const float* kps  = (const float*)d_in[1];  // (16,2,17,2)
    const float* frm0 = (const float*)d_in[2];  // (16,3,384,384)
    const float* frm1 = (const float*)d_in[3];  // (16,3,384,384)
    float* out = (float*)d_out;
    float* ws  = (float*)d_ws;

    char* base = (char*)d_ws;
    unsigned int* packed1 = (unsigned int*)(base + 64);
    unsigned int* packed0 = (unsigned int*)(base + 64 + (size_t)PACK_TOTAL * 4);
    float* partials4 = (float*)(base + 64 + (size_t)PACK_TOTAL * 4 + (size_t)NPIX * 4);

    const size_t need = 64 + (size_t)PACK_TOTAL * 4 + (size_t)NPIX * 4 +
                        (size_t)UNSUP4_BLOCKS * 4;
    if (ws_size >= need) {
        repack_kp_kernel<<<(PACK_TOTAL + 255) / 256, 256, 0, stream>>>(
            frm1, frm0, kps, pf, ws, packed1, packed0, 1);
        unsup4_kernel<<<UNSUP4_BLOCKS, 256, 0, stream>>>(pf, packed1, packed0, partials4);
        final_kernel<<<1, 1024, 0, stream>>>(ws, partials4, out, UNSUP4_BLOCKS);
    } else {
        float* partials1 = ws + 16;
        repack_kp_kernel<<<1, 256, 0, stream>>>(frm1, frm0, kps, pf, ws,
                                                packed1, packed0, 0);
        unsup1_kernel<<<UNSUP1_BLOCKS, 256, 0, stream>>>(pf, frm0, frm1, partials1);
        final_kernel<<<1, 1024, 0, stream>>>(ws, partials1, out, UNSUP1_BLOCKS);
    }
}